// Round 7
// baseline (126.563 us; speedup 1.0000x reference)
//
#include <hip/hip_runtime.h>
#include <hip/hip_bf16.h>
#include <stdint.h>

#define ENT 250000
#define RELSZ 64
#define D 128
#define BATCH 32768
#define KNEG 8

#define CAPP 2048  // pos exception capacity (expected ~17 for uniform labels)
#define CAPN 6144  // neg exception capacity (expected ~134)

// ---------------- workspace layout (byte offsets) ----------------
// t1    :      0 .. 32768   (64x128 f32)  out_rel - (n_inmap.out_rel) n_inmap
// t2    :  32768 .. 65536   (64x128 f32)  in_rel  - (n_outmap.in_rel) n_outmap
// RR    :  65536 .. 81920   (64x64  f32)  in_rel[i] . out_rel[p]
// hdr   :  81920 .. 82176   (2 int)       n_pos_exc, n_neg_exc
// E_pos :  82176 .. 90368   (2048 int)    sorted exceptional pos pair indices
// D_pos :  90368 .. 98560   (2048 int)    their sorted-output positions
// E_neg :  98560 .. 123136  (6144 int)
// D_neg : 123136 .. 147712  (6144 int)

__device__ __forceinline__ float logsig(float x) {
  return fminf(x, 0.f) - log1pf(expf(-fabsf(x)));
}

// Fused prep: blocks [0,32) tables (2 rel rows each), block 32 exception scan,
// blocks [33,65) zero d_out.
// NOTE: no device-scope fence / last-block pattern — R4 measured __threadfence()
// across 1184 blocks at ~73us on MI355X (non-coherent per-XCD L2). Kernel-boundary
// ordering is the cheap correct alternative. The exception pass is single-block,
// so only __syncthreads (block scope) is needed.
__global__ void k_prep(const float* __restrict__ in_rel, const float* __restrict__ out_rel,
                       const float* __restrict__ in_map, const float* __restrict__ out_map,
                       const int* __restrict__ in_lab, const int* __restrict__ pos_lab,
                       const int* __restrict__ neg_lab,
                       float* __restrict__ t1, float* __restrict__ t2, float* __restrict__ RR,
                       int* __restrict__ hdr, int* __restrict__ E_pos, int* __restrict__ D_pos,
                       int* __restrict__ E_neg, int* __restrict__ D_neg,
                       float* __restrict__ out) {
  __shared__ float ls[4];
  __shared__ float sri[2][128];
  __shared__ int vp[CAPP];
  __shared__ int vn[CAPN];
  __shared__ int cnt2[2];
  __shared__ int ckey[8];
  int blk = blockIdx.x, t = threadIdx.x;

  if (blk < 32) {
    // ---- tables: 2 rel rows per block ----
    int sub = t >> 7, tt = t & 127;
    int p = blk * 2 + sub;
    float im = in_map[p * D + tt], om = out_map[p * D + tt];
    float ro = out_rel[p * D + tt], ri = in_rel[p * D + tt];
    float v, r, n_im, n_om;
    v = im * im;
#pragma unroll
    for (int off = 32; off > 0; off >>= 1) v += __shfl_xor(v, off, 64);
    if ((t & 63) == 0) ls[t >> 6] = v;
    __syncthreads();
    r = ls[sub * 2] + ls[sub * 2 + 1];
    n_im = im / fmaxf(sqrtf(r), 1e-12f);
    __syncthreads();
    v = om * om;
#pragma unroll
    for (int off = 32; off > 0; off >>= 1) v += __shfl_xor(v, off, 64);
    if ((t & 63) == 0) ls[t >> 6] = v;
    __syncthreads();
    r = ls[sub * 2] + ls[sub * 2 + 1];
    n_om = om / fmaxf(sqrtf(r), 1e-12f);
    __syncthreads();
    v = n_im * ro;
#pragma unroll
    for (int off = 32; off > 0; off >>= 1) v += __shfl_xor(v, off, 64);
    if ((t & 63) == 0) ls[t >> 6] = v;
    __syncthreads();
    float d1 = ls[sub * 2] + ls[sub * 2 + 1];
    __syncthreads();
    v = n_om * ri;
#pragma unroll
    for (int off = 32; off > 0; off >>= 1) v += __shfl_xor(v, off, 64);
    if ((t & 63) == 0) ls[t >> 6] = v;
    __syncthreads();
    float d2 = ls[sub * 2] + ls[sub * 2 + 1];
    t1[p * D + tt] = ro - d1 * n_im;
    t2[p * D + tt] = ri - d2 * n_om;
    sri[sub][tt] = ri;
    __syncthreads();
    int half = t >> 7, lq = t & 127;
    if (lq < RELSZ) {
      int pr = blk * 2 + half;
      const float* rq = out_rel + lq * D;
      const float* s = sri[half];
      float acc = 0.f;
#pragma unroll 8
      for (int d = 0; d < D; d += 4) {
        float4 r4 = *(const float4*)(rq + d);
        acc += s[d] * r4.x + s[d + 1] * r4.y + s[d + 2] * r4.z + s[d + 3] * r4.w;
      }
      RR[pr * RELSZ + lq] = acc;
    }
    return;
  }

  if (blk >= 33) {
    // ---- zero d_out: 32 blocks x 256 threads x float4 = 32768 floats ----
    int idx = (blk - 33) * 256 + t;
    ((float4*)out)[idx] = make_float4(0.f, 0.f, 0.f, 0.f);
    return;
  }

  // ---- blk == 32: exception scan (single block; expected ~150 exceptions) ----
  if (t < 2) cnt2[t] = 0;
  if (t < 8) ckey[t] = 0;
  __syncthreads();
  for (int base = t * 4; base < BATCH; base += 1024) {
    int4 a = *(const int4*)(in_lab + base);
    int4 p4 = *(const int4*)(pos_lab + base);
    int ka[4];
    ka[0] = ((a.x >= ENT) ? 2 : 0) | ((p4.x >= ENT) ? 1 : 0);
    ka[1] = ((a.y >= ENT) ? 2 : 0) | ((p4.y >= ENT) ? 1 : 0);
    ka[2] = ((a.z >= ENT) ? 2 : 0) | ((p4.z >= ENT) ? 1 : 0);
    ka[3] = ((a.w >= ENT) ? 2 : 0) | ((p4.w >= ENT) ? 1 : 0);
#pragma unroll
    for (int j = 0; j < 4; j++)
      if (ka[j]) { int s = atomicAdd(&cnt2[0], 1); if (s < CAPP) vp[s] = ((base + j) << 2) | ka[j]; }
  }
  for (int row = t; row < BATCH; row += 256) {
    int il = in_lab[row];
    int kb = (il >= ENT) ? 2 : 0;
    int4 n0 = *(const int4*)(neg_lab + row * 8);
    int4 n1 = *(const int4*)(neg_lab + row * 8 + 4);
    int nv[8] = {n0.x, n0.y, n0.z, n0.w, n1.x, n1.y, n1.z, n1.w};
#pragma unroll
    for (int j = 0; j < 8; j++) {
      int key = kb | ((nv[j] >= ENT) ? 1 : 0);
      if (key) { int s = atomicAdd(&cnt2[1], 1); if (s < CAPN) vn[s] = (((row << 3) + j) << 2) | key; }
    }
  }
  __syncthreads();
  int np = min(cnt2[0], CAPP), nn = min(cnt2[1], CAPN);
  for (int j = t; j < np; j += 256) atomicAdd(&ckey[vp[j] & 3], 1);
  for (int j = t; j < nn; j += 256) atomicAdd(&ckey[4 + (vn[j] & 3)], 1);
  __syncthreads();
  int c1 = ckey[1], c2 = ckey[2], c3 = ckey[3];
  int N0p = BATCH - c1 - c2 - c3;
  int d1 = ckey[5], d2 = ckey[6], d3 = ckey[7];
  int N0n = BATCH * KNEG - d1 - d2 - d3;
  // v = (i<<2)|key : unique, ascending-v == ascending-i. For each exception,
  // sorted rank r = #{u < v}; same-key stable rank rk = #{u < v, key(u)==key(v)}.
  for (int j = t; j < np; j += 256) {
    int v = vp[j], key = v & 3;
    int r = 0, rk = 0;
    for (int m = 0; m < np; m++) {
      int u = vp[m];
      r += (u < v) ? 1 : 0;
      rk += ((u < v) && ((u & 3) == key)) ? 1 : 0;
    }
    int bbase = (key == 1) ? N0p : (key == 2) ? N0p + c1 : N0p + c1 + c2;
    E_pos[r] = v >> 2;
    D_pos[r] = bbase + rk;
  }
  for (int j = t; j < nn; j += 256) {
    int v = vn[j], key = v & 3;
    int r = 0, rk = 0;
    for (int m = 0; m < nn; m++) {
      int u = vn[m];
      r += (u < v) ? 1 : 0;
      rk += ((u < v) && ((u & 3) == key)) ? 1 : 0;
    }
    int bbase = (key == 1) ? N0n : (key == 2) ? N0n + d1 : N0n + d1 + d2;
    E_neg[r] = v >> 2;
    D_neg[r] = bbase + rk;
  }
  if (t == 0) { hdr[0] = np; hdr[1] = nn; }
}

// Main: 4 lanes per pair, 16 pairs per wave.
// Blocks [0,512): pos pairs. Blocks [512,4608): neg pairs (2 rows x 8 negs per wave).
// Sorted-output position: key==0 -> i - (#exceptions before i) via binary search over
// the tiny sorted E[] (L1-hot; search runs while row gathers are in flight);
// key!=0 -> exact dest from D[]. Negs tree-combine same-dest values into one atomic.
__global__ void __launch_bounds__(256, 4)
k_main(const float* __restrict__ in_ent, const float* __restrict__ out_ent,
       const float* __restrict__ t1, const float* __restrict__ t2,
       const float* __restrict__ RR,
       const int* __restrict__ in_lab, const int* __restrict__ pos_lab,
       const int* __restrict__ neg_lab,
       const int* __restrict__ hdr,
       const int* __restrict__ E_pos, const int* __restrict__ D_pos,
       const int* __restrict__ E_neg, const int* __restrict__ D_neg,
       float* __restrict__ out) {
  int blk = blockIdx.x, t = threadIdx.x;
  int wave = t >> 6, lane = t & 63;
  int q = lane & 3, g = lane >> 2;  // 16 groups of 4 lanes

  bool is_pos = blk < 512;
  int w = (is_pos ? blk : blk - 512) * 4 + wave;
  int i = w * 16 + g;  // pair index within its class

  int il, o;
  if (is_pos) { il = in_lab[i]; o = pos_lab[i]; }
  else        { il = in_lab[i >> 3]; o = neg_lab[i]; }
  bool ei = il < ENT;
  int iid = ei ? il : il - ENT;
  bool eo = o < ENT;
  int oid = eo ? o : o - ENT;
  int key = (ei ? 0 : 2) | (eo ? 0 : 1);

  // issue the 16 row loads first; the dest search below overlaps their latency
  const float* Lp = (ei ? in_ent + (size_t)iid * D : t2 + (size_t)iid * D) + q * 4;
  const float* Rp = (eo ? out_ent + (size_t)oid * D : t1 + (size_t)oid * D) + q * 4;
  float4 L[8], R[8];
#pragma unroll
  for (int k = 0; k < 8; k++) L[k] = *(const float4*)(Lp + k * 16);
#pragma unroll
  for (int k = 0; k < 8; k++) R[k] = *(const float4*)(Rp + k * 16);

  // binary search: lo = #exceptions with index < i (== exact slot when key!=0)
  int n = is_pos ? hdr[0] : hdr[1];
  const int* E = is_pos ? E_pos : E_neg;
  int lo = 0, hi = n;
  while (lo < hi) {
    int mid = (lo + hi) >> 1;
    bool lt = E[mid] < i;
    lo = lt ? mid + 1 : lo;
    hi = lt ? hi : mid;
  }
  int s = (key == 0) ? (i - lo) : (is_pos ? D_pos[lo] : D_neg[lo]);

  float p = 0.f;
#pragma unroll
  for (int k = 0; k < 8; k++)
    p += L[k].x * R[k].x + L[k].y * R[k].y + L[k].z * R[k].z + L[k].w * R[k].w;
  p += __shfl_xor(p, 1, 64);
  p += __shfl_xor(p, 2, 64);

  float dot = p;
  if (!ei && !eo) dot = RR[iid * RELSZ + oid];  // rel-rel pair: exact table value

  if (is_pos) {
    if (q == 0) atomicAdd(out + s, -logsig(dot));
    return;
  }

  // neg: dest uniform per group; tree-combine across the 8 groups of each 32-lane half
  int dest = s >> 3;
  float myval = (q == 0) ? -logsig(-dot) : 0.f;
  float v = myval;
  int d = dest;
  int eq = 1;
#pragma unroll
  for (int off = 4; off <= 16; off <<= 1) {
    float vv = __shfl_xor(v, off, 64);
    int dd = __shfl_xor(d, off, 64);
    int ee = __shfl_xor(eq, off, 64);
    eq = eq & ee & (dd == d ? 1 : 0);
    v += vv;
  }
  if (eq) {
    if (lane == 0 || lane == 32) atomicAdd(out + d, v);
  } else if (q == 0) {
    atomicAdd(out + dest, myval);
  }
}

extern "C" void kernel_launch(void* const* d_in, const int* in_sizes, int n_in,
                              void* d_out, int out_size, void* d_ws, size_t ws_size,
                              hipStream_t stream) {
  const float* in_ent  = (const float*)d_in[0];
  const float* out_ent = (const float*)d_in[1];
  const float* in_rel  = (const float*)d_in[2];
  const float* out_rel = (const float*)d_in[3];
  const float* in_map  = (const float*)d_in[4];
  const float* out_map = (const float*)d_in[5];
  const int* in_lab  = (const int*)d_in[6];
  const int* pos_lab = (const int*)d_in[7];
  const int* neg_lab = (const int*)d_in[8];

  char* ws = (char*)d_ws;
  float* t1    = (float*)(ws + 0);
  float* t2    = (float*)(ws + 32768);
  float* RR    = (float*)(ws + 65536);
  int*   hdr   = (int*)(ws + 81920);
  int*   E_pos = (int*)(ws + 82176);
  int*   D_pos = (int*)(ws + 90368);
  int*   E_neg = (int*)(ws + 98560);
  int*   D_neg = (int*)(ws + 123136);
  float* out   = (float*)d_out;

  k_prep<<<65, 256, 0, stream>>>(in_rel, out_rel, in_map, out_map,
                                 in_lab, pos_lab, neg_lab,
                                 t1, t2, RR, hdr, E_pos, D_pos, E_neg, D_neg, out);
  k_main<<<4608, 256, 0, stream>>>(in_ent, out_ent, t1, t2, RR,
                                   in_lab, pos_lab, neg_lab,
                                   hdr, E_pos, D_pos, E_neg, D_neg, out);
}

// Round 8
// 54.326 us; speedup vs baseline: 2.3297x; 2.3297x over previous
//
#include <hip/hip_runtime.h>
#include <hip/hip_bf16.h>
#include <stdint.h>

#define ENT 250000
#define RELSZ 64
#define D 128
#define BATCH 32768
#define KNEG 8

#define CAPP 2048  // pos exception capacity (expected ~17 for uniform labels)
#define CAPN 6144  // neg exception capacity (expected ~134)

// ---------------- workspace layout (byte offsets) ----------------
// t1    :      0 .. 32768   (64x128 f32)  out_rel - (n_inmap.out_rel) n_inmap
// t2    :  32768 .. 65536   (64x128 f32)  in_rel  - (n_outmap.in_rel) n_outmap
// RR    :  65536 .. 81920   (64x64  f32)  in_rel[i] . out_rel[p]
// hdr   :  81920 .. 81928   (2 int)       n_pos_exc, n_neg_exc
// E_pos :  82176 .. 90368   (2048 int)    sorted exceptional pos pair indices
// D_pos :  90368 .. 98560   (2048 int)    their sorted-output positions
// E_neg :  98560 .. 123136  (6144 int)
// D_neg : 123136 .. 147712  (6144 int)
// U_pos : 147712 .. 155904  (2048 int)    unsorted (row<<2)|key pushes
// U_neg : 155904 .. 180480  (6144 int)
// gcnt  : 180480 .. 180488  (2 int)       global push counters (memset to 0)

__device__ __forceinline__ float logsig(float x) {
  return fminf(x, 0.f) - log1pf(expf(-fabsf(x)));
}

// Fused prep: blocks [0,32) tables (2 rel rows each), [32,64) zero d_out,
// [64,192) parallel exception detect (one batch-row per thread; ballot-guarded
// global atomic pushes — expected ~150 total).
// NOTE (R4 lesson): no device-scope fence / last-block pattern — __threadfence()
// across 1k+ blocks measured ~73us on MI355X. Kernel-boundary ordering instead.
// NOTE (R7 lesson): never do a grid-serial scan in ONE block — 1.2MB from a
// single CU ran at ~10 GB/s = 122us. Detection must be grid-parallel.
__global__ void k_prep(const float* __restrict__ in_rel, const float* __restrict__ out_rel,
                       const float* __restrict__ in_map, const float* __restrict__ out_map,
                       const int* __restrict__ in_lab, const int* __restrict__ pos_lab,
                       const int* __restrict__ neg_lab,
                       float* __restrict__ t1, float* __restrict__ t2, float* __restrict__ RR,
                       int* __restrict__ U_pos, int* __restrict__ U_neg,
                       int* __restrict__ gcnt, float* __restrict__ out) {
  __shared__ float ls[4];
  __shared__ float sri[2][128];
  int blk = blockIdx.x, t = threadIdx.x;

  if (blk < 32) {
    // ---- tables: 2 rel rows per block ----
    int sub = t >> 7, tt = t & 127;
    int p = blk * 2 + sub;
    float im = in_map[p * D + tt], om = out_map[p * D + tt];
    float ro = out_rel[p * D + tt], ri = in_rel[p * D + tt];
    float v, r, n_im, n_om;
    v = im * im;
#pragma unroll
    for (int off = 32; off > 0; off >>= 1) v += __shfl_xor(v, off, 64);
    if ((t & 63) == 0) ls[t >> 6] = v;
    __syncthreads();
    r = ls[sub * 2] + ls[sub * 2 + 1];
    n_im = im / fmaxf(sqrtf(r), 1e-12f);
    __syncthreads();
    v = om * om;
#pragma unroll
    for (int off = 32; off > 0; off >>= 1) v += __shfl_xor(v, off, 64);
    if ((t & 63) == 0) ls[t >> 6] = v;
    __syncthreads();
    r = ls[sub * 2] + ls[sub * 2 + 1];
    n_om = om / fmaxf(sqrtf(r), 1e-12f);
    __syncthreads();
    v = n_im * ro;
#pragma unroll
    for (int off = 32; off > 0; off >>= 1) v += __shfl_xor(v, off, 64);
    if ((t & 63) == 0) ls[t >> 6] = v;
    __syncthreads();
    float d1 = ls[sub * 2] + ls[sub * 2 + 1];
    __syncthreads();
    v = n_om * ri;
#pragma unroll
    for (int off = 32; off > 0; off >>= 1) v += __shfl_xor(v, off, 64);
    if ((t & 63) == 0) ls[t >> 6] = v;
    __syncthreads();
    float d2 = ls[sub * 2] + ls[sub * 2 + 1];
    t1[p * D + tt] = ro - d1 * n_im;
    t2[p * D + tt] = ri - d2 * n_om;
    sri[sub][tt] = ri;
    __syncthreads();
    int half = t >> 7, lq = t & 127;
    if (lq < RELSZ) {
      int pr = blk * 2 + half;
      const float* rq = out_rel + lq * D;
      const float* s = sri[half];
      float acc = 0.f;
#pragma unroll 8
      for (int d = 0; d < D; d += 4) {
        float4 r4 = *(const float4*)(rq + d);
        acc += s[d] * r4.x + s[d + 1] * r4.y + s[d + 2] * r4.z + s[d + 3] * r4.w;
      }
      RR[pr * RELSZ + lq] = acc;
    }
    return;
  }

  if (blk < 64) {
    // ---- zero d_out: 32 blocks x 256 threads x float4 = 32768 floats ----
    int idx = (blk - 32) * 256 + t;
    ((float4*)out)[idx] = make_float4(0.f, 0.f, 0.f, 0.f);
    return;
  }

  // ---- parallel exception detect: one batch row per thread ----
  int row = (blk - 64) * 256 + t;
  int il = in_lab[row], pl = pos_lab[row];
  int kb = (il >= ENT) ? 2 : 0;
  int kp = kb | ((pl >= ENT) ? 1 : 0);
  int4 n0 = *(const int4*)(neg_lab + row * 8);
  int4 n1 = *(const int4*)(neg_lab + row * 8 + 4);
  int k0 = kb | ((n0.x >= ENT) ? 1 : 0), k1 = kb | ((n0.y >= ENT) ? 1 : 0);
  int k2 = kb | ((n0.z >= ENT) ? 1 : 0), k3 = kb | ((n0.w >= ENT) ? 1 : 0);
  int k4 = kb | ((n1.x >= ENT) ? 1 : 0), k5 = kb | ((n1.y >= ENT) ? 1 : 0);
  int k6 = kb | ((n1.z >= ENT) ? 1 : 0), k7 = kb | ((n1.w >= ENT) ? 1 : 0);
  bool has = (kp | k0 | k1 | k2 | k3 | k4 | k5 | k6 | k7) != 0;
  if (__ballot(has) == 0ull) return;  // ~85% of waves exit with zero atomics
  if (has) {
    if (kp) { int s = atomicAdd(gcnt, 1); if (s < CAPP) U_pos[s] = (row << 2) | kp; }
    int kv[8] = {k0, k1, k2, k3, k4, k5, k6, k7};
#pragma unroll
    for (int j = 0; j < 8; j++)
      if (kv[j]) {
        int s = atomicAdd(gcnt + 1, 1);
        if (s < CAPN) U_neg[s] = ((row * 8 + j) << 2) | kv[j];
      }
  }
}

// Single-block sort/rank of the ~150 exceptions. v=(i<<2)|key is unique and
// ascending-v == ascending-i, so rank r = #{u<v}; stable same-key rank likewise.
__global__ void k_sort(const int* __restrict__ U_pos, const int* __restrict__ U_neg,
                       const int* __restrict__ gcnt, int* __restrict__ hdr,
                       int* __restrict__ E_pos, int* __restrict__ D_pos,
                       int* __restrict__ E_neg, int* __restrict__ D_neg) {
  __shared__ int vp[CAPP];
  __shared__ int vn[CAPN];
  __shared__ int ckey[8];
  int t = threadIdx.x;
  int np = min(gcnt[0], CAPP), nn = min(gcnt[1], CAPN);
  if (t < 8) ckey[t] = 0;
  __syncthreads();
  for (int j = t; j < np; j += 256) vp[j] = U_pos[j];
  for (int j = t; j < nn; j += 256) vn[j] = U_neg[j];
  __syncthreads();
  for (int j = t; j < np; j += 256) atomicAdd(&ckey[vp[j] & 3], 1);
  for (int j = t; j < nn; j += 256) atomicAdd(&ckey[4 + (vn[j] & 3)], 1);
  __syncthreads();
  int c1 = ckey[1], c2 = ckey[2], c3 = ckey[3];
  int N0p = BATCH - c1 - c2 - c3;
  int d1 = ckey[5], d2 = ckey[6], d3 = ckey[7];
  int N0n = BATCH * KNEG - d1 - d2 - d3;
  for (int j = t; j < np; j += 256) {
    int v = vp[j], key = v & 3;
    int r = 0, rk = 0;
    for (int m = 0; m < np; m++) {
      int u = vp[m];
      r += (u < v) ? 1 : 0;
      rk += ((u < v) && ((u & 3) == key)) ? 1 : 0;
    }
    int bbase = (key == 1) ? N0p : (key == 2) ? N0p + c1 : N0p + c1 + c2;
    E_pos[r] = v >> 2;
    D_pos[r] = bbase + rk;
  }
  for (int j = t; j < nn; j += 256) {
    int v = vn[j], key = v & 3;
    int r = 0, rk = 0;
    for (int m = 0; m < nn; m++) {
      int u = vn[m];
      r += (u < v) ? 1 : 0;
      rk += ((u < v) && ((u & 3) == key)) ? 1 : 0;
    }
    int bbase = (key == 1) ? N0n : (key == 2) ? N0n + d1 : N0n + d1 + d2;
    E_neg[r] = v >> 2;
    D_neg[r] = bbase + rk;
  }
  if (t == 0) { hdr[0] = np; hdr[1] = nn; }
}

// Main: 4 lanes per pair, 16 pairs per wave.
// Blocks [0,512): pos pairs. Blocks [512,4608): neg pairs (2 rows x 8 negs per wave).
// Sorted-output position: key==0 -> i - (#exceptions before i) via binary search over
// the tiny sorted E[] (L1-hot; search overlaps the row-gather latency);
// key!=0 -> exact dest from D[]. Negs tree-combine same-dest values into one atomic.
__global__ void __launch_bounds__(256, 4)
k_main(const float* __restrict__ in_ent, const float* __restrict__ out_ent,
       const float* __restrict__ t1, const float* __restrict__ t2,
       const float* __restrict__ RR,
       const int* __restrict__ in_lab, const int* __restrict__ pos_lab,
       const int* __restrict__ neg_lab,
       const int* __restrict__ hdr,
       const int* __restrict__ E_pos, const int* __restrict__ D_pos,
       const int* __restrict__ E_neg, const int* __restrict__ D_neg,
       float* __restrict__ out) {
  int blk = blockIdx.x, t = threadIdx.x;
  int wave = t >> 6, lane = t & 63;
  int q = lane & 3, g = lane >> 2;  // 16 groups of 4 lanes

  bool is_pos = blk < 512;
  int w = (is_pos ? blk : blk - 512) * 4 + wave;
  int i = w * 16 + g;  // pair index within its class

  int il, o;
  if (is_pos) { il = in_lab[i]; o = pos_lab[i]; }
  else        { il = in_lab[i >> 3]; o = neg_lab[i]; }
  bool ei = il < ENT;
  int iid = ei ? il : il - ENT;
  bool eo = o < ENT;
  int oid = eo ? o : o - ENT;
  int key = (ei ? 0 : 2) | (eo ? 0 : 1);

  // issue the 16 row loads first; the dest search below overlaps their latency
  const float* Lp = (ei ? in_ent + (size_t)iid * D : t2 + (size_t)iid * D) + q * 4;
  const float* Rp = (eo ? out_ent + (size_t)oid * D : t1 + (size_t)oid * D) + q * 4;
  float4 L[8], R[8];
#pragma unroll
  for (int k = 0; k < 8; k++) L[k] = *(const float4*)(Lp + k * 16);
#pragma unroll
  for (int k = 0; k < 8; k++) R[k] = *(const float4*)(Rp + k * 16);

  // binary search: lo = #exceptions with index < i (== exact slot when key!=0)
  int n = is_pos ? hdr[0] : hdr[1];
  const int* E = is_pos ? E_pos : E_neg;
  int lo = 0, hi = n;
  while (lo < hi) {
    int mid = (lo + hi) >> 1;
    bool lt = E[mid] < i;
    lo = lt ? mid + 1 : lo;
    hi = lt ? hi : mid;
  }
  int s = (key == 0) ? (i - lo) : (is_pos ? D_pos[lo] : D_neg[lo]);

  float p = 0.f;
#pragma unroll
  for (int k = 0; k < 8; k++)
    p += L[k].x * R[k].x + L[k].y * R[k].y + L[k].z * R[k].z + L[k].w * R[k].w;
  p += __shfl_xor(p, 1, 64);
  p += __shfl_xor(p, 2, 64);

  float dot = p;
  if (!ei && !eo) dot = RR[iid * RELSZ + oid];  // rel-rel pair: exact table value

  if (is_pos) {
    if (q == 0) atomicAdd(out + s, -logsig(dot));
    return;
  }

  // neg: dest uniform per group; tree-combine across the 8 groups of each 32-lane half
  int dest = s >> 3;
  float myval = (q == 0) ? -logsig(-dot) : 0.f;
  float v = myval;
  int d = dest;
  int eq = 1;
#pragma unroll
  for (int off = 4; off <= 16; off <<= 1) {
    float vv = __shfl_xor(v, off, 64);
    int dd = __shfl_xor(d, off, 64);
    int ee = __shfl_xor(eq, off, 64);
    eq = eq & ee & (dd == d ? 1 : 0);
    v += vv;
  }
  if (eq) {
    if (lane == 0 || lane == 32) atomicAdd(out + d, v);
  } else if (q == 0) {
    atomicAdd(out + dest, myval);
  }
}

extern "C" void kernel_launch(void* const* d_in, const int* in_sizes, int n_in,
                              void* d_out, int out_size, void* d_ws, size_t ws_size,
                              hipStream_t stream) {
  const float* in_ent  = (const float*)d_in[0];
  const float* out_ent = (const float*)d_in[1];
  const float* in_rel  = (const float*)d_in[2];
  const float* out_rel = (const float*)d_in[3];
  const float* in_map  = (const float*)d_in[4];
  const float* out_map = (const float*)d_in[5];
  const int* in_lab  = (const int*)d_in[6];
  const int* pos_lab = (const int*)d_in[7];
  const int* neg_lab = (const int*)d_in[8];

  char* ws = (char*)d_ws;
  float* t1    = (float*)(ws + 0);
  float* t2    = (float*)(ws + 32768);
  float* RR    = (float*)(ws + 65536);
  int*   hdr   = (int*)(ws + 81920);
  int*   E_pos = (int*)(ws + 82176);
  int*   D_pos = (int*)(ws + 90368);
  int*   E_neg = (int*)(ws + 98560);
  int*   D_neg = (int*)(ws + 123136);
  int*   U_pos = (int*)(ws + 147712);
  int*   U_neg = (int*)(ws + 155904);
  int*   gcnt  = (int*)(ws + 180480);
  float* out   = (float*)d_out;

  hipMemsetAsync(gcnt, 0, 8, stream);
  k_prep<<<192, 256, 0, stream>>>(in_rel, out_rel, in_map, out_map,
                                  in_lab, pos_lab, neg_lab,
                                  t1, t2, RR, U_pos, U_neg, gcnt, out);
  k_sort<<<1, 256, 0, stream>>>(U_pos, U_neg, gcnt, hdr, E_pos, D_pos, E_neg, D_neg);
  k_main<<<4608, 256, 0, stream>>>(in_ent, out_ent, t1, t2, RR,
                                   in_lab, pos_lab, neg_lab,
                                   hdr, E_pos, D_pos, E_neg, D_neg, out);
}

// Round 9
// 52.251 us; speedup vs baseline: 2.4222x; 1.0397x over previous
//
#include <hip/hip_runtime.h>
#include <hip/hip_bf16.h>
#include <stdint.h>

#define ENT 250000
#define RELSZ 64
#define D 128
#define BATCH 32768
#define KNEG 8

#define CAPP 2048  // pos exception capacity (expected ~17 for uniform labels)
#define CAPN 6144  // neg exception capacity (expected ~134)

// ---------------- workspace layout (byte offsets) ----------------
// t1    :      0 .. 32768    (64x128 f32)  out_rel - (n_inmap.out_rel) n_inmap
// t2    :  32768 .. 65536    (64x128 f32)  in_rel  - (n_outmap.in_rel) n_outmap
// RR    :  65536 .. 81920    (64x64  f32)  in_rel[i] . out_rel[p]
// hdr   :  81920 .. 81928    (2 int)       n_pos_exc, n_neg_exc
// E_pos :  82176 .. 90368    (2048 int)    sorted exceptional pos pair indices
// D_pos :  90368 .. 98560    (2048 int)    their sorted-output positions
// E_neg :  98560 .. 123136   (6144 int)
// D_neg : 123136 .. 147712   (6144 int)
// cntp  : 147712 .. 148224   (128 int)     per-detect-block exception counts
// cntn  : 148224 .. 148736   (128 int)
// U_pos : 148736 .. 279808   (128 x 256 int)   per-block slots, unsorted
// U_neg : 279808 .. 1328384  (128 x 2048 int)
// NOTE (R8 lesson): NO hipMemsetAsync on scratch — an 8-byte graph-captured fill
// dispatch measured 72us. Every pass initializes what it owns (counts written
// unconditionally per block).

__device__ __forceinline__ float logsig(float x) {
  return fminf(x, 0.f) - log1pf(expf(-fabsf(x)));
}

// Fused prep: blocks [0,32) tables (2 rel rows each), [32,64) zero d_out,
// [64,192) parallel exception detect into per-block slots.
// NOTE (R4 lesson): no device-scope fence / last-block pattern — __threadfence()
// across 1k+ blocks measured ~73us on MI355X. Kernel-boundary ordering instead.
// NOTE (R7 lesson): never do a grid-serial scan in ONE block — 1.2MB from a
// single CU ran at ~10 GB/s = 122us. Detection must be grid-parallel.
__global__ void k_prep(const float* __restrict__ in_rel, const float* __restrict__ out_rel,
                       const float* __restrict__ in_map, const float* __restrict__ out_map,
                       const int* __restrict__ in_lab, const int* __restrict__ pos_lab,
                       const int* __restrict__ neg_lab,
                       float* __restrict__ t1, float* __restrict__ t2, float* __restrict__ RR,
                       int* __restrict__ U_pos, int* __restrict__ U_neg,
                       int* __restrict__ cntp, int* __restrict__ cntn,
                       float* __restrict__ out) {
  __shared__ float ls[4];
  __shared__ float sri[2][128];
  __shared__ int sp[256];
  __shared__ int sn[2048];
  __shared__ int sc[2];
  int blk = blockIdx.x, t = threadIdx.x;

  if (blk < 32) {
    // ---- tables: 2 rel rows per block ----
    int sub = t >> 7, tt = t & 127;
    int p = blk * 2 + sub;
    float im = in_map[p * D + tt], om = out_map[p * D + tt];
    float ro = out_rel[p * D + tt], ri = in_rel[p * D + tt];
    float v, r, n_im, n_om;
    v = im * im;
#pragma unroll
    for (int off = 32; off > 0; off >>= 1) v += __shfl_xor(v, off, 64);
    if ((t & 63) == 0) ls[t >> 6] = v;
    __syncthreads();
    r = ls[sub * 2] + ls[sub * 2 + 1];
    n_im = im / fmaxf(sqrtf(r), 1e-12f);
    __syncthreads();
    v = om * om;
#pragma unroll
    for (int off = 32; off > 0; off >>= 1) v += __shfl_xor(v, off, 64);
    if ((t & 63) == 0) ls[t >> 6] = v;
    __syncthreads();
    r = ls[sub * 2] + ls[sub * 2 + 1];
    n_om = om / fmaxf(sqrtf(r), 1e-12f);
    __syncthreads();
    v = n_im * ro;
#pragma unroll
    for (int off = 32; off > 0; off >>= 1) v += __shfl_xor(v, off, 64);
    if ((t & 63) == 0) ls[t >> 6] = v;
    __syncthreads();
    float d1 = ls[sub * 2] + ls[sub * 2 + 1];
    __syncthreads();
    v = n_om * ri;
#pragma unroll
    for (int off = 32; off > 0; off >>= 1) v += __shfl_xor(v, off, 64);
    if ((t & 63) == 0) ls[t >> 6] = v;
    __syncthreads();
    float d2 = ls[sub * 2] + ls[sub * 2 + 1];
    t1[p * D + tt] = ro - d1 * n_im;
    t2[p * D + tt] = ri - d2 * n_om;
    sri[sub][tt] = ri;
    __syncthreads();
    int half = t >> 7, lq = t & 127;
    if (lq < RELSZ) {
      int pr = blk * 2 + half;
      const float* rq = out_rel + lq * D;
      const float* s = sri[half];
      float acc = 0.f;
#pragma unroll 8
      for (int d = 0; d < D; d += 4) {
        float4 r4 = *(const float4*)(rq + d);
        acc += s[d] * r4.x + s[d + 1] * r4.y + s[d + 2] * r4.z + s[d + 3] * r4.w;
      }
      RR[pr * RELSZ + lq] = acc;
    }
    return;
  }

  if (blk < 64) {
    // ---- zero d_out: 32 blocks x 256 threads x float4 = 32768 floats ----
    int idx = (blk - 32) * 256 + t;
    ((float4*)out)[idx] = make_float4(0.f, 0.f, 0.f, 0.f);
    return;
  }

  // ---- parallel exception detect: one batch row per thread, per-block slots ----
  if (t < 2) sc[t] = 0;
  __syncthreads();
  int bb = blk - 64;
  int row = bb * 256 + t;
  int il = in_lab[row], pl = pos_lab[row];
  int kb = (il >= ENT) ? 2 : 0;
  int kp = kb | ((pl >= ENT) ? 1 : 0);
  int4 n0 = *(const int4*)(neg_lab + row * 8);
  int4 n1 = *(const int4*)(neg_lab + row * 8 + 4);
  int k0 = kb | ((n0.x >= ENT) ? 1 : 0), k1 = kb | ((n0.y >= ENT) ? 1 : 0);
  int k2 = kb | ((n0.z >= ENT) ? 1 : 0), k3 = kb | ((n0.w >= ENT) ? 1 : 0);
  int k4 = kb | ((n1.x >= ENT) ? 1 : 0), k5 = kb | ((n1.y >= ENT) ? 1 : 0);
  int k6 = kb | ((n1.z >= ENT) ? 1 : 0), k7 = kb | ((n1.w >= ENT) ? 1 : 0);
  bool has = (kp | k0 | k1 | k2 | k3 | k4 | k5 | k6 | k7) != 0;
  if (has) {
    if (kp) { int s = atomicAdd(&sc[0], 1); sp[s] = (row << 2) | kp; }
    int kv[8] = {k0, k1, k2, k3, k4, k5, k6, k7};
#pragma unroll
    for (int j = 0; j < 8; j++)
      if (kv[j]) { int s = atomicAdd(&sc[1], 1); sn[s] = ((row * 8 + j) << 2) | kv[j]; }
  }
  __syncthreads();
  int np = sc[0], nn = sc[1];
  for (int j = t; j < np; j += 256) U_pos[bb * 256 + j] = sp[j];
  for (int j = t; j < nn; j += 256) U_neg[bb * 2048 + j] = sn[j];
  if (t == 0) { cntp[bb] = np; cntn[bb] = nn; }
}

// Single-block compaction + sort/rank of the ~150 exceptions. v=(i<<2)|key is
// unique and ascending-v == ascending-i, so rank r = #{u<v}; same-key stable
// rank likewise. Compaction order is irrelevant (rank is by value).
__global__ void k_sort(const int* __restrict__ U_pos, const int* __restrict__ U_neg,
                       const int* __restrict__ cntp, const int* __restrict__ cntn,
                       int* __restrict__ hdr,
                       int* __restrict__ E_pos, int* __restrict__ D_pos,
                       int* __restrict__ E_neg, int* __restrict__ D_neg) {
  __shared__ int vp[CAPP];
  __shared__ int vn[CAPN];
  __shared__ int c2[2];
  __shared__ int ckey[8];
  int t = threadIdx.x;
  if (t < 2) c2[t] = 0;
  if (t < 8) ckey[t] = 0;
  __syncthreads();
  for (int b = t; b < 128; b += 256) {
    int cp = cntp[b];
    if (cp > 0) {
      int base = atomicAdd(&c2[0], cp);
      for (int j = 0; j < cp && base + j < CAPP; j++) vp[base + j] = U_pos[b * 256 + j];
    }
    int cn = cntn[b];
    if (cn > 0) {
      int base = atomicAdd(&c2[1], cn);
      for (int j = 0; j < cn && base + j < CAPN; j++) vn[base + j] = U_neg[b * 2048 + j];
    }
  }
  __syncthreads();
  int np = min(c2[0], CAPP), nn = min(c2[1], CAPN);
  for (int j = t; j < np; j += 256) atomicAdd(&ckey[vp[j] & 3], 1);
  for (int j = t; j < nn; j += 256) atomicAdd(&ckey[4 + (vn[j] & 3)], 1);
  __syncthreads();
  int c1 = ckey[1], cc2 = ckey[2], c3 = ckey[3];
  int N0p = BATCH - c1 - cc2 - c3;
  int d1 = ckey[5], d2 = ckey[6], d3 = ckey[7];
  int N0n = BATCH * KNEG - d1 - d2 - d3;
  for (int j = t; j < np; j += 256) {
    int v = vp[j], key = v & 3;
    int r = 0, rk = 0;
    for (int m = 0; m < np; m++) {
      int u = vp[m];
      r += (u < v) ? 1 : 0;
      rk += ((u < v) && ((u & 3) == key)) ? 1 : 0;
    }
    int bbase = (key == 1) ? N0p : (key == 2) ? N0p + c1 : N0p + c1 + cc2;
    E_pos[r] = v >> 2;
    D_pos[r] = bbase + rk;
  }
  for (int j = t; j < nn; j += 256) {
    int v = vn[j], key = v & 3;
    int r = 0, rk = 0;
    for (int m = 0; m < nn; m++) {
      int u = vn[m];
      r += (u < v) ? 1 : 0;
      rk += ((u < v) && ((u & 3) == key)) ? 1 : 0;
    }
    int bbase = (key == 1) ? N0n : (key == 2) ? N0n + d1 : N0n + d1 + d2;
    E_neg[r] = v >> 2;
    D_neg[r] = bbase + rk;
  }
  if (t == 0) { hdr[0] = np; hdr[1] = nn; }
}

// Main: 4 lanes per pair, 16 pairs per wave.
// Blocks [0,512): pos pairs. Blocks [512,4608): neg pairs (2 rows x 8 negs per wave).
// Sorted-output position: key==0 -> i - (#exceptions before i) via binary search over
// the tiny sorted E[] (L1-hot; search overlaps the row-gather latency);
// key!=0 -> exact dest from D[]. Negs tree-combine same-dest values into one atomic.
__global__ void __launch_bounds__(256, 4)
k_main(const float* __restrict__ in_ent, const float* __restrict__ out_ent,
       const float* __restrict__ t1, const float* __restrict__ t2,
       const float* __restrict__ RR,
       const int* __restrict__ in_lab, const int* __restrict__ pos_lab,
       const int* __restrict__ neg_lab,
       const int* __restrict__ hdr,
       const int* __restrict__ E_pos, const int* __restrict__ D_pos,
       const int* __restrict__ E_neg, const int* __restrict__ D_neg,
       float* __restrict__ out) {
  int blk = blockIdx.x, t = threadIdx.x;
  int wave = t >> 6, lane = t & 63;
  int q = lane & 3, g = lane >> 2;  // 16 groups of 4 lanes

  bool is_pos = blk < 512;
  int w = (is_pos ? blk : blk - 512) * 4 + wave;
  int i = w * 16 + g;  // pair index within its class

  int il, o;
  if (is_pos) { il = in_lab[i]; o = pos_lab[i]; }
  else        { il = in_lab[i >> 3]; o = neg_lab[i]; }
  bool ei = il < ENT;
  int iid = ei ? il : il - ENT;
  bool eo = o < ENT;
  int oid = eo ? o : o - ENT;
  int key = (ei ? 0 : 2) | (eo ? 0 : 1);

  // issue the 16 row loads first; the dest search below overlaps their latency
  const float* Lp = (ei ? in_ent + (size_t)iid * D : t2 + (size_t)iid * D) + q * 4;
  const float* Rp = (eo ? out_ent + (size_t)oid * D : t1 + (size_t)oid * D) + q * 4;
  float4 L[8], R[8];
#pragma unroll
  for (int k = 0; k < 8; k++) L[k] = *(const float4*)(Lp + k * 16);
#pragma unroll
  for (int k = 0; k < 8; k++) R[k] = *(const float4*)(Rp + k * 16);

  // binary search: lo = #exceptions with index < i (== exact slot when key!=0)
  int n = is_pos ? hdr[0] : hdr[1];
  const int* E = is_pos ? E_pos : E_neg;
  int lo = 0, hi = n;
  while (lo < hi) {
    int mid = (lo + hi) >> 1;
    bool lt = E[mid] < i;
    lo = lt ? mid + 1 : lo;
    hi = lt ? hi : mid;
  }
  int s = (key == 0) ? (i - lo) : (is_pos ? D_pos[lo] : D_neg[lo]);

  float p = 0.f;
#pragma unroll
  for (int k = 0; k < 8; k++)
    p += L[k].x * R[k].x + L[k].y * R[k].y + L[k].z * R[k].z + L[k].w * R[k].w;
  p += __shfl_xor(p, 1, 64);
  p += __shfl_xor(p, 2, 64);

  float dot = p;
  if (!ei && !eo) dot = RR[iid * RELSZ + oid];  // rel-rel pair: exact table value

  if (is_pos) {
    if (q == 0) atomicAdd(out + s, -logsig(dot));
    return;
  }

  // neg: dest uniform per group; tree-combine across the 8 groups of each 32-lane half
  int dest = s >> 3;
  float myval = (q == 0) ? -logsig(-dot) : 0.f;
  float v = myval;
  int d = dest;
  int eq = 1;
#pragma unroll
  for (int off = 4; off <= 16; off <<= 1) {
    float vv = __shfl_xor(v, off, 64);
    int dd = __shfl_xor(d, off, 64);
    int ee = __shfl_xor(eq, off, 64);
    eq = eq & ee & (dd == d ? 1 : 0);
    v += vv;
  }
  if (eq) {
    if (lane == 0 || lane == 32) atomicAdd(out + d, v);
  } else if (q == 0) {
    atomicAdd(out + dest, myval);
  }
}

extern "C" void kernel_launch(void* const* d_in, const int* in_sizes, int n_in,
                              void* d_out, int out_size, void* d_ws, size_t ws_size,
                              hipStream_t stream) {
  const float* in_ent  = (const float*)d_in[0];
  const float* out_ent = (const float*)d_in[1];
  const float* in_rel  = (const float*)d_in[2];
  const float* out_rel = (const float*)d_in[3];
  const float* in_map  = (const float*)d_in[4];
  const float* out_map = (const float*)d_in[5];
  const int* in_lab  = (const int*)d_in[6];
  const int* pos_lab = (const int*)d_in[7];
  const int* neg_lab = (const int*)d_in[8];

  char* ws = (char*)d_ws;
  float* t1    = (float*)(ws + 0);
  float* t2    = (float*)(ws + 32768);
  float* RR    = (float*)(ws + 65536);
  int*   hdr   = (int*)(ws + 81920);
  int*   E_pos = (int*)(ws + 82176);
  int*   D_pos = (int*)(ws + 90368);
  int*   E_neg = (int*)(ws + 98560);
  int*   D_neg = (int*)(ws + 123136);
  int*   cntp  = (int*)(ws + 147712);
  int*   cntn  = (int*)(ws + 148224);
  int*   U_pos = (int*)(ws + 148736);
  int*   U_neg = (int*)(ws + 279808);
  float* out   = (float*)d_out;

  k_prep<<<192, 256, 0, stream>>>(in_rel, out_rel, in_map, out_map,
                                  in_lab, pos_lab, neg_lab,
                                  t1, t2, RR, U_pos, U_neg, cntp, cntn, out);
  k_sort<<<1, 256, 0, stream>>>(U_pos, U_neg, cntp, cntn, hdr,
                                E_pos, D_pos, E_neg, D_neg);
  k_main<<<4608, 256, 0, stream>>>(in_ent, out_ent, t1, t2, RR,
                                   in_lab, pos_lab, neg_lab,
                                   hdr, E_pos, D_pos, E_neg, D_neg, out);
}

// Round 10
// 50.439 us; speedup vs baseline: 2.5092x; 1.0359x over previous
//
#include <hip/hip_runtime.h>
#include <hip/hip_bf16.h>
#include <stdint.h>

#define ENT 250000
#define RELSZ 64
#define D 128
#define BATCH 32768
#define KNEG 8

#define CAPP 2048  // pos exception capacity (expected ~17 for uniform labels)
#define CAPN 6144  // neg exception capacity (expected ~134)
#define LCAP 1024  // k_main LDS staging capacity (fallback to global search beyond)

// ---------------- workspace layout (byte offsets) ----------------
// t1    :      0 .. 32768    (64x128 f32)  out_rel - (n_inmap.out_rel) n_inmap
// t2    :  32768 .. 65536    (64x128 f32)  in_rel  - (n_outmap.in_rel) n_outmap
// RR    :  65536 .. 81920    (64x64  f32)  in_rel[i] . out_rel[p]
// hdr   :  81920 .. 81928    (2 int)       n_pos_exc, n_neg_exc
// E_pos :  82176 .. 90368    (2048 int)    sorted exceptional pos pair indices
// D_pos :  90368 .. 98560    (2048 int)    their sorted-output positions
// E_neg :  98560 .. 123136   (6144 int)
// D_neg : 123136 .. 147712   (6144 int)
// cntp  : 147712 .. 148224   (128 int)     per-detect-block exception counts
// cntn  : 148224 .. 148736   (128 int)
// U_pos : 148736 .. 279808   (128 x 256 int)   per-block slots, unsorted
// U_neg : 279808 .. 1328384  (128 x 2048 int)
// NOTE (R8 lesson): NO hipMemsetAsync on scratch — an 8-byte graph-captured fill
// dispatch measured ~72us. Every pass initializes what it owns.

__device__ __forceinline__ float logsig(float x) {
  return fminf(x, 0.f) - log1pf(expf(-fabsf(x)));
}

// Fused prep: blocks [0,32) tables (2 rel rows each), [32,64) zero d_out,
// [64,192) parallel exception detect into per-block slots.
// NOTE (R4 lesson): no device-scope fence / last-block pattern — __threadfence()
// across 1k+ blocks measured ~73us on MI355X. Kernel-boundary ordering instead.
// NOTE (R7 lesson): never grid-serial-scan in ONE block — 1.2MB from a single CU
// ran at ~10 GB/s = 122us. Detection must be grid-parallel.
__global__ void k_prep(const float* __restrict__ in_rel, const float* __restrict__ out_rel,
                       const float* __restrict__ in_map, const float* __restrict__ out_map,
                       const int* __restrict__ in_lab, const int* __restrict__ pos_lab,
                       const int* __restrict__ neg_lab,
                       float* __restrict__ t1, float* __restrict__ t2, float* __restrict__ RR,
                       int* __restrict__ U_pos, int* __restrict__ U_neg,
                       int* __restrict__ cntp, int* __restrict__ cntn,
                       float* __restrict__ out) {
  __shared__ float ls[4];
  __shared__ float sri[2][128];
  __shared__ int sp[256];
  __shared__ int sn[2048];
  __shared__ int sc[2];
  int blk = blockIdx.x, t = threadIdx.x;

  if (blk < 32) {
    // ---- tables: 2 rel rows per block ----
    int sub = t >> 7, tt = t & 127;
    int p = blk * 2 + sub;
    float im = in_map[p * D + tt], om = out_map[p * D + tt];
    float ro = out_rel[p * D + tt], ri = in_rel[p * D + tt];
    float v, r, n_im, n_om;
    v = im * im;
#pragma unroll
    for (int off = 32; off > 0; off >>= 1) v += __shfl_xor(v, off, 64);
    if ((t & 63) == 0) ls[t >> 6] = v;
    __syncthreads();
    r = ls[sub * 2] + ls[sub * 2 + 1];
    n_im = im / fmaxf(sqrtf(r), 1e-12f);
    __syncthreads();
    v = om * om;
#pragma unroll
    for (int off = 32; off > 0; off >>= 1) v += __shfl_xor(v, off, 64);
    if ((t & 63) == 0) ls[t >> 6] = v;
    __syncthreads();
    r = ls[sub * 2] + ls[sub * 2 + 1];
    n_om = om / fmaxf(sqrtf(r), 1e-12f);
    __syncthreads();
    v = n_im * ro;
#pragma unroll
    for (int off = 32; off > 0; off >>= 1) v += __shfl_xor(v, off, 64);
    if ((t & 63) == 0) ls[t >> 6] = v;
    __syncthreads();
    float d1 = ls[sub * 2] + ls[sub * 2 + 1];
    __syncthreads();
    v = n_om * ri;
#pragma unroll
    for (int off = 32; off > 0; off >>= 1) v += __shfl_xor(v, off, 64);
    if ((t & 63) == 0) ls[t >> 6] = v;
    __syncthreads();
    float d2 = ls[sub * 2] + ls[sub * 2 + 1];
    t1[p * D + tt] = ro - d1 * n_im;
    t2[p * D + tt] = ri - d2 * n_om;
    sri[sub][tt] = ri;
    __syncthreads();
    int half = t >> 7, lq = t & 127;
    if (lq < RELSZ) {
      int pr = blk * 2 + half;
      const float* rq = out_rel + lq * D;
      const float* s = sri[half];
      float acc = 0.f;
#pragma unroll 8
      for (int d = 0; d < D; d += 4) {
        float4 r4 = *(const float4*)(rq + d);
        acc += s[d] * r4.x + s[d + 1] * r4.y + s[d + 2] * r4.z + s[d + 3] * r4.w;
      }
      RR[pr * RELSZ + lq] = acc;
    }
    return;
  }

  if (blk < 64) {
    // ---- zero d_out: 32 blocks x 256 threads x float4 = 32768 floats ----
    int idx = (blk - 32) * 256 + t;
    ((float4*)out)[idx] = make_float4(0.f, 0.f, 0.f, 0.f);
    return;
  }

  // ---- parallel exception detect: one batch row per thread, per-block slots ----
  if (t < 2) sc[t] = 0;
  __syncthreads();
  int bb = blk - 64;
  int row = bb * 256 + t;
  int il = in_lab[row], pl = pos_lab[row];
  int kb = (il >= ENT) ? 2 : 0;
  int kp = kb | ((pl >= ENT) ? 1 : 0);
  int4 n0 = *(const int4*)(neg_lab + row * 8);
  int4 n1 = *(const int4*)(neg_lab + row * 8 + 4);
  int k0 = kb | ((n0.x >= ENT) ? 1 : 0), k1 = kb | ((n0.y >= ENT) ? 1 : 0);
  int k2 = kb | ((n0.z >= ENT) ? 1 : 0), k3 = kb | ((n0.w >= ENT) ? 1 : 0);
  int k4 = kb | ((n1.x >= ENT) ? 1 : 0), k5 = kb | ((n1.y >= ENT) ? 1 : 0);
  int k6 = kb | ((n1.z >= ENT) ? 1 : 0), k7 = kb | ((n1.w >= ENT) ? 1 : 0);
  bool has = (kp | k0 | k1 | k2 | k3 | k4 | k5 | k6 | k7) != 0;
  if (has) {
    if (kp) { int s = atomicAdd(&sc[0], 1); sp[s] = (row << 2) | kp; }
    int kv[8] = {k0, k1, k2, k3, k4, k5, k6, k7};
#pragma unroll
    for (int j = 0; j < 8; j++)
      if (kv[j]) { int s = atomicAdd(&sc[1], 1); sn[s] = ((row * 8 + j) << 2) | kv[j]; }
  }
  __syncthreads();
  int np = sc[0], nn = sc[1];
  for (int j = t; j < np; j += 256) U_pos[bb * 256 + j] = sp[j];
  for (int j = t; j < nn; j += 256) U_neg[bb * 2048 + j] = sn[j];
  if (t == 0) { cntp[bb] = np; cntn[bb] = nn; }
}

// Single-block compaction + sort/rank of the ~150 exceptions. v=(i<<2)|key is
// unique and ascending-v == ascending-i, so rank r = #{u<v}; same-key stable
// rank likewise. Compaction order is irrelevant (rank is by value).
__global__ void k_sort(const int* __restrict__ U_pos, const int* __restrict__ U_neg,
                       const int* __restrict__ cntp, const int* __restrict__ cntn,
                       int* __restrict__ hdr,
                       int* __restrict__ E_pos, int* __restrict__ D_pos,
                       int* __restrict__ E_neg, int* __restrict__ D_neg) {
  __shared__ int vp[CAPP];
  __shared__ int vn[CAPN];
  __shared__ int c2[2];
  __shared__ int ckey[8];
  int t = threadIdx.x;
  if (t < 2) c2[t] = 0;
  if (t < 8) ckey[t] = 0;
  __syncthreads();
  for (int b = t; b < 128; b += 256) {
    int cp = cntp[b];
    if (cp > 0) {
      int base = atomicAdd(&c2[0], cp);
      for (int j = 0; j < cp && base + j < CAPP; j++) vp[base + j] = U_pos[b * 256 + j];
    }
    int cn = cntn[b];
    if (cn > 0) {
      int base = atomicAdd(&c2[1], cn);
      for (int j = 0; j < cn && base + j < CAPN; j++) vn[base + j] = U_neg[b * 2048 + j];
    }
  }
  __syncthreads();
  int np = min(c2[0], CAPP), nn = min(c2[1], CAPN);
  for (int j = t; j < np; j += 256) atomicAdd(&ckey[vp[j] & 3], 1);
  for (int j = t; j < nn; j += 256) atomicAdd(&ckey[4 + (vn[j] & 3)], 1);
  __syncthreads();
  int c1 = ckey[1], cc2 = ckey[2], c3 = ckey[3];
  int N0p = BATCH - c1 - cc2 - c3;
  int d1 = ckey[5], d2 = ckey[6], d3 = ckey[7];
  int N0n = BATCH * KNEG - d1 - d2 - d3;
  for (int j = t; j < np; j += 256) {
    int v = vp[j], key = v & 3;
    int r = 0, rk = 0;
    for (int m = 0; m < np; m++) {
      int u = vp[m];
      r += (u < v) ? 1 : 0;
      rk += ((u < v) && ((u & 3) == key)) ? 1 : 0;
    }
    int bbase = (key == 1) ? N0p : (key == 2) ? N0p + c1 : N0p + c1 + cc2;
    E_pos[r] = v >> 2;
    D_pos[r] = bbase + rk;
  }
  for (int j = t; j < nn; j += 256) {
    int v = vn[j], key = v & 3;
    int r = 0, rk = 0;
    for (int m = 0; m < nn; m++) {
      int u = vn[m];
      r += (u < v) ? 1 : 0;
      rk += ((u < v) && ((u & 3) == key)) ? 1 : 0;
    }
    int bbase = (key == 1) ? N0n : (key == 2) ? N0n + d1 : N0n + d1 + d2;
    E_neg[r] = v >> 2;
    D_neg[r] = bbase + rk;
  }
  if (t == 0) { hdr[0] = np; hdr[1] = nn; }
}

// Main: 4 lanes per pair, 16 pairs per wave.
// Blocks [0,512): pos pairs. Blocks [512,4608): neg pairs (2 rows x 8 negs/wave).
// NOTE (R9 lesson): vmcnt is IN-ORDER — a dependent chain of global loads issued
// after the row gathers forces draining the gathers at every step. The exception
// search therefore runs from LDS (lgkmcnt), staged ONCE per block BEFORE the row
// loads are issued; the ds_read search chain then hides fully under gather latency.
__global__ void __launch_bounds__(256, 4)
k_main(const float* __restrict__ in_ent, const float* __restrict__ out_ent,
       const float* __restrict__ t1, const float* __restrict__ t2,
       const float* __restrict__ RR,
       const int* __restrict__ in_lab, const int* __restrict__ pos_lab,
       const int* __restrict__ neg_lab,
       const int* __restrict__ hdr,
       const int* __restrict__ E_pos, const int* __restrict__ D_pos,
       const int* __restrict__ E_neg, const int* __restrict__ D_neg,
       float* __restrict__ out) {
  __shared__ int sE[LCAP];
  __shared__ int sD[LCAP];
  int blk = blockIdx.x, t = threadIdx.x;
  int wave = t >> 6, lane = t & 63;
  int q = lane & 3, g = lane >> 2;  // 16 groups of 4 lanes

  bool is_pos = blk < 512;
  int w = (is_pos ? blk : blk - 512) * 4 + wave;
  int i = w * 16 + g;  // pair index within its class

  // issue label loads first (latency hides under the staging below)
  int il, o;
  if (is_pos) { il = in_lab[i]; o = pos_lab[i]; }
  else        { il = in_lab[i >> 3]; o = neg_lab[i]; }

  // stage exception tables to LDS (block-wide, once)
  const int* E = is_pos ? E_pos : E_neg;
  const int* Dd = is_pos ? D_pos : D_neg;
  int n = hdr[is_pos ? 0 : 1];
  bool lds_ok = (n <= LCAP);
  if (lds_ok) {
    for (int j = t; j < n; j += 256) { sE[j] = E[j]; sD[j] = Dd[j]; }
  }
  __syncthreads();

  bool ei = il < ENT;
  int iid = ei ? il : il - ENT;
  bool eo = o < ENT;
  int oid = eo ? o : o - ENT;
  int key = (ei ? 0 : 2) | (eo ? 0 : 1);

  // issue the 16 row gathers
  const float* Lp = (ei ? in_ent + (size_t)iid * D : t2 + (size_t)iid * D) + q * 4;
  const float* Rp = (eo ? out_ent + (size_t)oid * D : t1 + (size_t)oid * D) + q * 4;
  float4 L[8], R[8];
#pragma unroll
  for (int k = 0; k < 8; k++) L[k] = *(const float4*)(Lp + k * 16);
#pragma unroll
  for (int k = 0; k < 8; k++) R[k] = *(const float4*)(Rp + k * 16);

  // binary search (LDS; lgkmcnt-only, overlaps the gathers):
  // lo = #exceptions with index < i (== exact slot when key!=0)
  int lo = 0, hi = n;
  if (lds_ok) {
    while (lo < hi) {
      int mid = (lo + hi) >> 1;
      bool lt = sE[mid] < i;
      lo = lt ? mid + 1 : lo;
      hi = lt ? hi : mid;
    }
  } else {
    while (lo < hi) {
      int mid = (lo + hi) >> 1;
      bool lt = E[mid] < i;
      lo = lt ? mid + 1 : lo;
      hi = lt ? hi : mid;
    }
  }
  int s = (key == 0) ? (i - lo) : (lds_ok ? sD[lo] : Dd[lo]);

  float p = 0.f;
#pragma unroll
  for (int k = 0; k < 8; k++)
    p += L[k].x * R[k].x + L[k].y * R[k].y + L[k].z * R[k].z + L[k].w * R[k].w;
  p += __shfl_xor(p, 1, 64);
  p += __shfl_xor(p, 2, 64);

  float dot = p;
  if (!ei && !eo) dot = RR[iid * RELSZ + oid];  // rel-rel pair: exact table value

  if (is_pos) {
    if (q == 0) atomicAdd(out + s, -logsig(dot));
    return;
  }

  // neg: dest uniform per group; tree-combine across the 8 groups of each half
  int dest = s >> 3;
  float myval = (q == 0) ? -logsig(-dot) : 0.f;
  float v = myval;
  int d = dest;
  int eq = 1;
#pragma unroll
  for (int off = 4; off <= 16; off <<= 1) {
    float vv = __shfl_xor(v, off, 64);
    int dd = __shfl_xor(d, off, 64);
    int ee = __shfl_xor(eq, off, 64);
    eq = eq & ee & (dd == d ? 1 : 0);
    v += vv;
  }
  if (eq) {
    if (lane == 0 || lane == 32) atomicAdd(out + d, v);
  } else if (q == 0) {
    atomicAdd(out + dest, myval);
  }
}

extern "C" void kernel_launch(void* const* d_in, const int* in_sizes, int n_in,
                              void* d_out, int out_size, void* d_ws, size_t ws_size,
                              hipStream_t stream) {
  const float* in_ent  = (const float*)d_in[0];
  const float* out_ent = (const float*)d_in[1];
  const float* in_rel  = (const float*)d_in[2];
  const float* out_rel = (const float*)d_in[3];
  const float* in_map  = (const float*)d_in[4];
  const float* out_map = (const float*)d_in[5];
  const int* in_lab  = (const int*)d_in[6];
  const int* pos_lab = (const int*)d_in[7];
  const int* neg_lab = (const int*)d_in[8];

  char* ws = (char*)d_ws;
  float* t1    = (float*)(ws + 0);
  float* t2    = (float*)(ws + 32768);
  float* RR    = (float*)(ws + 65536);
  int*   hdr   = (int*)(ws + 81920);
  int*   E_pos = (int*)(ws + 82176);
  int*   D_pos = (int*)(ws + 90368);
  int*   E_neg = (int*)(ws + 98560);
  int*   D_neg = (int*)(ws + 123136);
  int*   cntp  = (int*)(ws + 147712);
  int*   cntn  = (int*)(ws + 148224);
  int*   U_pos = (int*)(ws + 148736);
  int*   U_neg = (int*)(ws + 279808);
  float* out   = (float*)d_out;

  k_prep<<<192, 256, 0, stream>>>(in_rel, out_rel, in_map, out_map,
                                  in_lab, pos_lab, neg_lab,
                                  t1, t2, RR, U_pos, U_neg, cntp, cntn, out);
  k_sort<<<1, 256, 0, stream>>>(U_pos, U_neg, cntp, cntn, hdr,
                                E_pos, D_pos, E_neg, D_neg);
  k_main<<<4608, 256, 0, stream>>>(in_ent, out_ent, t1, t2, RR,
                                   in_lab, pos_lab, neg_lab,
                                   hdr, E_pos, D_pos, E_neg, D_neg, out);
}